// Round 2
// baseline (31442.401 us; speedup 1.0000x reference)
//
#include <hip/hip_runtime.h>

// VanillaRNN: S=512, I=1, H=256, C=10, B=2048, all fp32.
// h:[256, B] recurrence; batch independent -> 256 blocks x 8 batch, all 512
// steps inside one kernel. W_hh register-resident (512 thr x 4rows x 32cols).
// h in double-buffered, bank-swizzled LDS. j-split reduced via DPP butterfly.
//
// R2: __launch_bounds__(512, 1) -- the R1 (512,2) capped VGPRs at 128 and
// spilled the entire W register tile to scratch (94 GB HBM traffic, VALUBusy
// 6%). One block/CU needs 2 waves/SIMD -> hard cap 256 VGPRs, no spill.

#define SEQ  512
#define HID  256
#define NCLS 10
#define NB   8      // batch per block
#define NT   512    // threads per block (8 waves)

template <int CTRL>
__device__ __forceinline__ float dpp_xor_add(float v) {
    int mv = __builtin_amdgcn_update_dpp(0, __float_as_int(v), CTRL, 0xf, 0xf, false);
    return v + __int_as_float(mv);
}

__device__ __forceinline__ float fast_tanh(float z) {
    // tanh(z) = 1 - 2/(e^{2z}+1); exp overflow/underflow saturate correctly.
    float e = __expf(2.0f * z);
    return 1.0f - 2.0f / (e + 1.0f);
}

// h LDS layout: phys(j,b) = j*8 + (j>>5)*4 + b  (swizzle -> conflict-free
// broadcast reads: bank = (4*jg + 8k + b) & 31, distinct per jg)
__global__ __launch_bounds__(NT, 1) void rnn_fused(
    const float* __restrict__ x,     // [B, S]
    const float* __restrict__ W_hx,  // [H, 1]
    const float* __restrict__ W_hh,  // [H, H]
    const float* __restrict__ W_ph,  // [C, H]
    const float* __restrict__ b_h,   // [H]
    const float* __restrict__ b_p,   // [C]
    float* __restrict__ out)         // [B, C]
{
    __shared__ __align__(16) float h_lds[2][2080];
    __shared__ __align__(16) float x_lds[SEQ][NB];   // [t][b]

    const int tid  = threadIdx.x;
    const int lane = tid & 63;
    const int wave = tid >> 6;
    // jg from lane bits {0,1,3} (DPP-reducible); rg from bits {2,4,5} + wave
    const int jg = (lane & 3) | ((lane & 8) >> 1);                    // 0..7
    const int rg = wave * 8 + ((lane >> 4) << 1) + ((lane & 4) >> 2); // 0..63
    const int r0 = rg * 4;      // rows r0..r0+3
    const int j0 = jg * 32;     // cols j0..j0+31
    const int b0 = blockIdx.x * NB;

    // ---- stage W_hh slice into registers: w[4][32] ----
    float w[4][32];
#pragma unroll
    for (int r = 0; r < 4; ++r) {
        const float4* wp = (const float4*)&W_hh[(r0 + r) * HID + j0];
#pragma unroll
        for (int kk = 0; kk < 8; ++kk) {
            float4 v = wp[kk];
            w[r][kk * 4 + 0] = v.x; w[r][kk * 4 + 1] = v.y;
            w[r][kk * 4 + 2] = v.z; w[r][kk * 4 + 3] = v.w;
        }
    }
    float wx[4], bh[4];
#pragma unroll
    for (int r = 0; r < 4; ++r) { wx[r] = W_hx[r0 + r]; bh[r] = b_h[r0 + r]; }

    // ---- stage x transposed into LDS: x_lds[t][b] = x[b0+b][t] ----
    for (int i = tid; i < NB * SEQ / 4; i += NT) {
        int b  = i >> 7;            // / (SEQ/4)
        int t4 = (i & 127) * 4;
        float4 v = *(const float4*)&x[(b0 + b) * SEQ + t4];
        x_lds[t4 + 0][b] = v.x; x_lds[t4 + 1][b] = v.y;
        x_lds[t4 + 2][b] = v.z; x_lds[t4 + 3][b] = v.w;
    }
    // ---- h0 = 0 ----
    for (int i = tid; i < 2 * 2080; i += NT) ((float*)h_lds)[i] = 0.0f;
    __syncthreads();

    int cur = 0;
    for (int t = 0; t < SEQ; ++t) {
        float4 xv0 = *(const float4*)&x_lds[t][0];
        float4 xv1 = *(const float4*)&x_lds[t][4];

        float acc[4][NB];
#pragma unroll
        for (int r = 0; r < 4; ++r)
#pragma unroll
            for (int b = 0; b < NB; ++b) acc[r][b] = 0.0f;

        // thread's h window is contiguous: float offset 260*jg + 8k
        const float4* hp = (const float4*)&h_lds[cur][260 * jg];
#pragma unroll
        for (int k = 0; k < 32; ++k) {
            float4 h0 = hp[2 * k];
            float4 h1 = hp[2 * k + 1];
#pragma unroll
            for (int r = 0; r < 4; ++r) {
                float wv = w[r][k];
                acc[r][0] += wv * h0.x; acc[r][1] += wv * h0.y;
                acc[r][2] += wv * h0.z; acc[r][3] += wv * h0.w;
                acc[r][4] += wv * h1.x; acc[r][5] += wv * h1.y;
                acc[r][6] += wv * h1.z; acc[r][7] += wv * h1.w;
            }
        }

        // butterfly all-reduce over the 8 jg lanes (lane bits 0,1,3) on VALU
#pragma unroll
        for (int r = 0; r < 4; ++r)
#pragma unroll
            for (int b = 0; b < NB; ++b) {
                float v = acc[r][b];
                v = dpp_xor_add<0xB1>(v);    // quad_perm(1,0,3,2): xor 1
                v = dpp_xor_add<0x4E>(v);    // quad_perm(2,3,0,1): xor 2
                v = dpp_xor_add<0x128>(v);   // row_ror:8          : xor 8
                acc[r][b] = v;
            }

        // lane jg finalizes row r0+(jg>>1), batch quad (jg&1)*4
        float s0 = 0, s1 = 0, s2 = 0, s3 = 0, wxs = 0, bhs = 0;
#pragma unroll
        for (int g = 0; g < 8; ++g)
            if (jg == g) {
                const int rr = g >> 1, bb = (g & 1) * 4;
                s0 = acc[rr][bb + 0]; s1 = acc[rr][bb + 1];
                s2 = acc[rr][bb + 2]; s3 = acc[rr][bb + 3];
                wxs = wx[rr]; bhs = bh[rr];
            }
        float4 xv = (jg & 1) ? xv1 : xv0;

        const int nxt  = cur ^ 1;
        const int wrow = r0 + (jg >> 1);
        const int woff = wrow * 8 + (wrow >> 5) * 4 + (jg & 1) * 4;
        float4 hnew;
        hnew.x = fast_tanh(s0 + wxs * xv.x + bhs);
        hnew.y = fast_tanh(s1 + wxs * xv.y + bhs);
        hnew.z = fast_tanh(s2 + wxs * xv.z + bhs);
        hnew.w = fast_tanh(s3 + wxs * xv.w + bhs);
        *(float4*)&h_lds[nxt][woff] = hnew;
        cur = nxt;
        __syncthreads();
    }

    // ---- epilogue: out[b][c] = b_p[c] + sum_j W_ph[c][j] * h[j][b] ----
    if (tid < NB * NCLS) {
        int b = tid / NCLS;
        int c = tid % NCLS;
        float sum = b_p[c];
        for (int j = 0; j < HID; ++j)
            sum += W_ph[c * HID + j] * h_lds[cur][j * 8 + (j >> 5) * 4 + b];
        out[(b0 + b) * NCLS + c] = sum;
    }
}

extern "C" void kernel_launch(void* const* d_in, const int* in_sizes, int n_in,
                              void* d_out, int out_size, void* d_ws, size_t ws_size,
                              hipStream_t stream) {
    const float* x    = (const float*)d_in[0];
    const float* W_hx = (const float*)d_in[1];
    const float* W_hh = (const float*)d_in[2];
    const float* W_ph = (const float*)d_in[3];
    const float* b_h  = (const float*)d_in[4];
    const float* b_p  = (const float*)d_in[5];
    float* out = (float*)d_out;

    rnn_fused<<<dim3(2048 / NB), dim3(NT), 0, stream>>>(
        x, W_hx, W_hh, W_ph, b_h, b_p, out);
}

// Round 3
// 1847.822 us; speedup vs baseline: 17.0159x; 17.0159x over previous
//
#include <hip/hip_runtime.h>

// VanillaRNN: S=512, I=1, H=256, C=10, B=2048, all fp32.
// h:[256, B] recurrence; batch independent -> 256 blocks x 8 batch, all 512
// steps inside one kernel. W_hh register-resident across the block.
//
// R3: R1/R2 spilled (VGPR capped at 128 by the allocator's occupancy target;
// launch_bounds(.,1) is a min-waves FLOOR and cannot raise the budget).
// Restructure: 1024 threads/block, 2 rows x 32 cols of W per thread
// (64 regs) -> ~105 live regs, fits the 128 budget. waves_per_eu(4,4)
// pins exactly 4 waves/SIMD (16-wave block, 1 block/CU).

#define SEQ  512
#define HID  256
#define NCLS 10
#define NB   8       // batch per block
#define NT   1024    // threads per block (16 waves)

template <int CTRL>
__device__ __forceinline__ float dpp_xor_add(float v) {
    int mv = __builtin_amdgcn_update_dpp(0, __float_as_int(v), CTRL, 0xf, 0xf, false);
    return v + __int_as_float(mv);
}

__device__ __forceinline__ float fast_tanh(float z) {
    // tanh(z) = 1 - 2/(e^{2z}+1); exp overflow/underflow saturate correctly.
    float e = __expf(2.0f * z);
    return 1.0f - 2.0f / (e + 1.0f);
}

// h LDS layout: phys(j,b) = j*8 + (j>>5)*4 + b  (swizzle -> conflict-free
// broadcast reads: word-bank = (4*jg + 8k + b) & 31, distinct span per jg)
__global__ __launch_bounds__(NT)
__attribute__((amdgpu_waves_per_eu(4, 4)))
void rnn_fused(
    const float* __restrict__ x,     // [B, S]
    const float* __restrict__ W_hx,  // [H, 1]
    const float* __restrict__ W_hh,  // [H, H]
    const float* __restrict__ W_ph,  // [C, H]
    const float* __restrict__ b_h,   // [H]
    const float* __restrict__ b_p,   // [C]
    float* __restrict__ out)         // [B, C]
{
    __shared__ __align__(16) float h_lds[2][2080];
    __shared__ __align__(16) float x_lds[SEQ][NB];   // [t][b]

    const int tid  = threadIdx.x;
    const int lane = tid & 63;
    const int wave = tid >> 6;                       // 0..15
    // jg from lane bits {0,1,3} (DPP-reducible); rsub from bits {2,4,5}
    const int jg   = (lane & 3) | ((lane & 8) >> 1);                 // 0..7
    const int rsub = (((lane >> 4) & 3) << 1) | ((lane & 4) >> 2);   // 0..7
    const int rg = wave * 8 + rsub;   // 0..127
    const int r0 = rg * 2;            // rows r0, r0+1
    const int j0 = jg * 32;           // cols j0..j0+31
    const int b0 = blockIdx.x * NB;

    // ---- stage W_hh slice into registers: w[2][32] ----
    float w[2][32];
#pragma unroll
    for (int r = 0; r < 2; ++r) {
        const float4* wp = (const float4*)&W_hh[(r0 + r) * HID + j0];
#pragma unroll
        for (int kk = 0; kk < 8; ++kk) {
            float4 v = wp[kk];
            w[r][kk * 4 + 0] = v.x; w[r][kk * 4 + 1] = v.y;
            w[r][kk * 4 + 2] = v.z; w[r][kk * 4 + 3] = v.w;
        }
    }
    float wx[2], bh[2];
#pragma unroll
    for (int r = 0; r < 2; ++r) { wx[r] = W_hx[r0 + r]; bh[r] = b_h[r0 + r]; }

    // ---- stage x transposed into LDS: x_lds[t][b] = x[b0+b][t] ----
    for (int i = tid; i < NB * SEQ / 4; i += NT) {
        int b  = i >> 7;            // / (SEQ/4)
        int t4 = (i & 127) * 4;
        float4 v = *(const float4*)&x[(b0 + b) * SEQ + t4];
        x_lds[t4 + 0][b] = v.x; x_lds[t4 + 1][b] = v.y;
        x_lds[t4 + 2][b] = v.z; x_lds[t4 + 3][b] = v.w;
    }
    // ---- h0 = 0 ----
    for (int i = tid; i < 2 * 2080; i += NT) ((float*)h_lds)[i] = 0.0f;
    __syncthreads();

    // this thread finalizes rows r0+(jg&1), batches bb, bb+1
    const int bb   = (jg >> 1) * 2;
    const int wrow = r0 + (jg & 1);
    const int woff = wrow * 8 + (wrow >> 5) * 4 + bb;
    const float wxs = wx[jg & 1];
    const float bhs = bh[jg & 1];

    int cur = 0;
    for (int t = 0; t < SEQ; ++t) {
        float2 xv = *(const float2*)&x_lds[t][bb];

        float acc[2][NB];
#pragma unroll
        for (int r = 0; r < 2; ++r)
#pragma unroll
            for (int b = 0; b < NB; ++b) acc[r][b] = 0.0f;

        // thread's h window is contiguous: float offset 260*jg + 8k
        const float4* hp = (const float4*)&h_lds[cur][260 * jg];
#pragma unroll
        for (int k = 0; k < 32; ++k) {
            float4 h0 = hp[2 * k];
            float4 h1 = hp[2 * k + 1];
#pragma unroll
            for (int r = 0; r < 2; ++r) {
                float wv = w[r][k];
                acc[r][0] += wv * h0.x; acc[r][1] += wv * h0.y;
                acc[r][2] += wv * h0.z; acc[r][3] += wv * h0.w;
                acc[r][4] += wv * h1.x; acc[r][5] += wv * h1.y;
                acc[r][6] += wv * h1.z; acc[r][7] += wv * h1.w;
            }
        }

        // butterfly all-reduce over the 8 jg lanes (lane bits 0,1,3) on VALU
#pragma unroll
        for (int r = 0; r < 2; ++r)
#pragma unroll
            for (int b = 0; b < NB; ++b) {
                float v = acc[r][b];
                v = dpp_xor_add<0xB1>(v);    // quad_perm(1,0,3,2): xor 1
                v = dpp_xor_add<0x4E>(v);    // quad_perm(2,3,0,1): xor 2
                v = dpp_xor_add<0x128>(v);   // row_ror:8          : xor 8
                acc[r][b] = v;
            }

        // lane jg finalizes row r0+(jg&1), batch pair bb=(jg>>1)*2
        float s0 = 0.0f, s1 = 0.0f;
#pragma unroll
        for (int g = 0; g < 8; ++g)
            if (jg == g) {
                s0 = acc[g & 1][(g >> 1) * 2 + 0];
                s1 = acc[g & 1][(g >> 1) * 2 + 1];
            }

        const int nxt = cur ^ 1;
        float2 hnew;
        hnew.x = fast_tanh(s0 + wxs * xv.x + bhs);
        hnew.y = fast_tanh(s1 + wxs * xv.y + bhs);
        *(float2*)&h_lds[nxt][woff] = hnew;
        cur = nxt;
        __syncthreads();
    }

    // ---- epilogue: out[b][c] = b_p[c] + sum_j W_ph[c][j] * h[j][b] ----
    if (tid < NB * NCLS) {
        int b = tid / NCLS;
        int c = tid % NCLS;
        float sum = b_p[c];
        for (int j = 0; j < HID; ++j)
            sum += W_ph[c * HID + j] * h_lds[cur][j * 8 + (j >> 5) * 4 + b];
        out[(b0 + b) * NCLS + c] = sum;
    }
}

extern "C" void kernel_launch(void* const* d_in, const int* in_sizes, int n_in,
                              void* d_out, int out_size, void* d_ws, size_t ws_size,
                              hipStream_t stream) {
    const float* x    = (const float*)d_in[0];
    const float* W_hx = (const float*)d_in[1];
    const float* W_hh = (const float*)d_in[2];
    const float* W_ph = (const float*)d_in[3];
    const float* b_h  = (const float*)d_in[4];
    const float* b_p  = (const float*)d_in[5];
    float* out = (float*)d_out;

    rnn_fused<<<dim3(2048 / NB), dim3(NT), 0, stream>>>(
        x, W_hx, W_hh, W_ph, b_h, b_p, out);
}

// Round 4
// 493.519 us; speedup vs baseline: 63.7107x; 3.7442x over previous
//
#include <hip/hip_runtime.h>

// VanillaRNN: S=512, I=1, H=256, C=10, B=2048, fp32 in/out.
// R4: MFMA path. Block = 16 batch (128 blocks), 8 waves.
// Per step: pre[256,16] = W_hh(f16,reg) @ h(f16,LDS) via 16x16x32 f16 MFMA
// (fp32 accum), + W_hx*x_t + b_h in fp32, tanh, h' -> f16 LDS (dbuf).
// Wave owns 2 m-tiles (rows wave*32..+31): A-frags = 64 VGPR, fits the
// 128-VGPR budget the allocator targets (R1/R2 lesson: never exceed it).
// hT[n][k] pitch 264 f16 -> bank shift 4/row: 2-way max aliasing (free).

#define SEQ   512
#define HID   256
#define NCLS  10
#define BN    16      // batch per block
#define NT    512     // 8 waves
#define PITCH 264     // f16 pitch for hT rows (256 + 8)

typedef _Float16 f16x8 __attribute__((ext_vector_type(8)));
typedef _Float16 f16x4 __attribute__((ext_vector_type(4)));
typedef float    f32x4 __attribute__((ext_vector_type(4)));

__device__ __forceinline__ float fast_tanh(float z) {
    // tanh(z) = 1 - 2/(e^{2z}+1); saturates correctly at +-inf.
    float e = __expf(2.0f * z);
    return 1.0f - 2.0f / (e + 1.0f);
}

__global__ __launch_bounds__(NT) void rnn_mfma(
    const float* __restrict__ x,     // [B, S]
    const float* __restrict__ W_hx,  // [H]
    const float* __restrict__ W_hh,  // [H, H]
    const float* __restrict__ W_ph,  // [C, H]
    const float* __restrict__ b_h,   // [H]
    const float* __restrict__ b_p,   // [C]
    float* __restrict__ out)         // [B, C]
{
    __shared__ __align__(16) _Float16 hT[2][BN][PITCH];  // 16.5 KB
    __shared__ __align__(16) float xs[SEQ][17];          // 34 KB

    const int tid  = threadIdx.x;
    const int lane = tid & 63;
    const int wave = tid >> 6;       // 0..7
    const int n16  = lane & 15;      // MFMA n / batch-col index
    const int quad = lane >> 4;      // 0..3
    const int b0   = blockIdx.x * BN;

    // ---- A-fragments: W_hh fp32 -> f16, wave owns rows [wave*32, wave*32+32)
    // A[m = lane&15][k = quad*8 + j]  (m120-verified operand layout)
    f16x8 afrag[2][8];
#pragma unroll
    for (int mt = 0; mt < 2; ++mt) {
        const int row = wave * 32 + mt * 16 + n16;
#pragma unroll
        for (int ks = 0; ks < 8; ++ks) {
            const float4* p = (const float4*)&W_hh[row * HID + ks * 32 + quad * 8];
            float4 u = p[0], v = p[1];
            f16x8 a;
            a[0] = (_Float16)u.x; a[1] = (_Float16)u.y;
            a[2] = (_Float16)u.z; a[3] = (_Float16)u.w;
            a[4] = (_Float16)v.x; a[5] = (_Float16)v.y;
            a[6] = (_Float16)v.z; a[7] = (_Float16)v.w;
            afrag[mt][ks] = a;
        }
    }
    // bias / W_hx for the rows this lane's D covers: row = base + quad*4 + r
    float bh[2][4], wx[2][4];
#pragma unroll
    for (int mt = 0; mt < 2; ++mt)
#pragma unroll
        for (int r = 0; r < 4; ++r) {
            const int row = wave * 32 + mt * 16 + quad * 4 + r;
            bh[mt][r] = b_h[row];
            wx[mt][r] = W_hx[row];
        }

    // ---- stage x transposed: xs[t][n] = x[b0+n][t] ----
    for (int i = tid; i < BN * SEQ / 4; i += NT) {
        const int n = i >> 7, t4 = (i & 127) * 4;
        float4 v = *(const float4*)&x[(b0 + n) * SEQ + t4];
        xs[t4 + 0][n] = v.x; xs[t4 + 1][n] = v.y;
        xs[t4 + 2][n] = v.z; xs[t4 + 3][n] = v.w;
    }
    // ---- h0 = 0 ----
    for (int i = tid; i < BN * PITCH; i += NT)
        ((_Float16*)hT[0])[i] = (_Float16)0.0f;
    __syncthreads();

    int cur = 0;
    for (int t = 0; t < SEQ; ++t) {
        f32x4 acc0 = {0.f, 0.f, 0.f, 0.f};
        f32x4 acc1 = {0.f, 0.f, 0.f, 0.f};
        // B[k = quad*8 + j][n = lane&15] = hT[n][quad*8 + j + 32*ks]
        const _Float16* bp = &hT[cur][n16][quad * 8];
#pragma unroll
        for (int ks = 0; ks < 8; ++ks) {
            f16x8 b = *(const f16x8*)(bp + ks * 32);   // ds_read_b128
            acc0 = __builtin_amdgcn_mfma_f32_16x16x32_f16(afrag[0][ks], b, acc0, 0, 0, 0);
            acc1 = __builtin_amdgcn_mfma_f32_16x16x32_f16(afrag[1][ks], b, acc1, 0, 0, 0);
        }
        const float xv  = xs[t][n16];
        const int   nxt = cur ^ 1;
        {
            f16x4 h4;
#pragma unroll
            for (int r = 0; r < 4; ++r)
                h4[r] = (_Float16)fast_tanh(acc0[r] + wx[0][r] * xv + bh[0][r]);
            *(f16x4*)&hT[nxt][n16][wave * 32 + quad * 4] = h4;       // ds_write_b64
        }
        {
            f16x4 h4;
#pragma unroll
            for (int r = 0; r < 4; ++r)
                h4[r] = (_Float16)fast_tanh(acc1[r] + wx[1][r] * xv + bh[1][r]);
            *(f16x4*)&hT[nxt][n16][wave * 32 + 16 + quad * 4] = h4;
        }
        cur = nxt;
        __syncthreads();
    }

    // ---- output: out[b][c] = b_p[c] + sum_j W_ph[c][j] * h_final[j][b] ----
    if (tid < BN * NCLS) {
        const int b = tid / NCLS, c = tid % NCLS;
        float sum = b_p[c];
        const _Float16* hp = hT[cur][b];   // h_final[j][b] = hT[b][j]
        for (int j = 0; j < HID; ++j)
            sum += W_ph[c * HID + j] * (float)hp[j];
        out[(b0 + b) * NCLS + c] = sum;
    }
}

extern "C" void kernel_launch(void* const* d_in, const int* in_sizes, int n_in,
                              void* d_out, int out_size, void* d_ws, size_t ws_size,
                              hipStream_t stream) {
    const float* x    = (const float*)d_in[0];
    const float* W_hx = (const float*)d_in[1];
    const float* W_hh = (const float*)d_in[2];
    const float* W_ph = (const float*)d_in[3];
    const float* b_h  = (const float*)d_in[4];
    const float* b_p  = (const float*)d_in[5];
    float* out = (float*)d_out;

    rnn_mfma<<<dim3(2048 / BN), dim3(NT), 0, stream>>>(
        x, W_hx, W_hh, W_ph, b_h, b_p, out);
}

// Round 5
// 396.952 us; speedup vs baseline: 79.2096x; 1.2433x over previous
//
#include <hip/hip_runtime.h>

// VanillaRNN: S=512, I=1, H=256, C=10, B=2048, fp32 in/out.
// R5: 128 blocks x 4 waves (NT=256, 1 wave/SIMD). Wave owns 64 rows =
// 4 m-tiles of 16x16x32 f16 MFMA. Halves LDS traffic vs R4 (32 b128/CU/step).
// hT XOR-swizzled (chunk c of row n at c^(n&7), pitch 256) -> conflict-free.
// Weights pre-scaled by 2*log2e: tanh = 1 - 2*rcp(exp2(s)+1), bias in MFMA C.
// amdgpu_waves_per_eu(1,1) -> 512-VGPR budget, no spill (R1/R2 lesson).

#define SEQ   512
#define HID   256
#define NCLS  10
#define BN    16      // batch per block
#define NT    256     // 4 waves

typedef _Float16 f16x8 __attribute__((ext_vector_type(8)));
typedef _Float16 f16x4 __attribute__((ext_vector_type(4)));
typedef float    f32x4 __attribute__((ext_vector_type(4)));

__global__ __launch_bounds__(NT)
__attribute__((amdgpu_waves_per_eu(1, 1)))
void rnn_mfma(
    const float* __restrict__ x,     // [B, S]
    const float* __restrict__ W_hx,  // [H]
    const float* __restrict__ W_hh,  // [H, H]
    const float* __restrict__ W_ph,  // [C, H]
    const float* __restrict__ b_h,   // [H]
    const float* __restrict__ b_p,   // [C]
    float* __restrict__ out)         // [B, C]
{
    // hT[buf][n][k]: k-chunk c (8 f16) stored at physical chunk c ^ (n&7)
    __shared__ __align__(16) _Float16 hT[2][BN][HID];   // 16 KB
    __shared__ __align__(16) float xs[SEQ][BN];          // 32 KB

    const int tid  = threadIdx.x;
    const int lane = tid & 63;
    const int wave = tid >> 6;       // 0..3
    const int n16  = lane & 15;
    const int quad = lane >> 4;      // 0..3
    const int e    = n16 & 7;
    const int b0   = blockIdx.x * BN;

    const float SC = 2.885390081777926814f;   // 2*log2(e)

    // ---- A-frags: rows [wave*64, wave*64+64), pre-scaled by SC, f16 ----
    // A[m = n16][k = quad*8 + j]
    f16x8 afrag[4][8];
#pragma unroll
    for (int mt = 0; mt < 4; ++mt) {
        const int row = wave * 64 + mt * 16 + n16;
#pragma unroll
        for (int ks = 0; ks < 8; ++ks) {
            const float4* p = (const float4*)&W_hh[row * HID + ks * 32 + quad * 8];
            float4 u = p[0], v = p[1];
            f16x8 a;
            a[0] = (_Float16)(SC * u.x); a[1] = (_Float16)(SC * u.y);
            a[2] = (_Float16)(SC * u.z); a[3] = (_Float16)(SC * u.w);
            a[4] = (_Float16)(SC * v.x); a[5] = (_Float16)(SC * v.y);
            a[6] = (_Float16)(SC * v.z); a[7] = (_Float16)(SC * v.w);
            afrag[mt][ks] = a;
        }
    }
    // D rows for this lane: row = wave*64 + mt*16 + quad*4 + r
    f32x4 bias[4], wxv[4];
#pragma unroll
    for (int mt = 0; mt < 4; ++mt)
#pragma unroll
        for (int r = 0; r < 4; ++r) {
            const int row = wave * 64 + mt * 16 + quad * 4 + r;
            bias[mt][r] = SC * b_h[row];
            wxv[mt][r]  = SC * W_hx[row];
        }

    // ---- precomputed swizzled byte offsets (within one buffer) ----
    int roff[8], woff[4];
#pragma unroll
    for (int ks = 0; ks < 8; ++ks)
        roff[ks] = (n16 * HID + (((4 * ks + quad) ^ e) << 3)) * 2;
#pragma unroll
    for (int mt = 0; mt < 4; ++mt)
        woff[mt] = (n16 * HID +
                    (((8 * wave + 2 * mt + (quad >> 1)) ^ e) << 3) +
                    (quad & 1) * 4) * 2;

    // ---- stage xs[t][n] = x[b0+n][t] ----
    for (int i = tid; i < BN * SEQ / 4; i += NT) {
        const int n = i >> 7, t4 = (i & 127) * 4;
        float4 v = *(const float4*)&x[(b0 + n) * SEQ + t4];
        xs[t4 + 0][n] = v.x; xs[t4 + 1][n] = v.y;
        xs[t4 + 2][n] = v.z; xs[t4 + 3][n] = v.w;
    }
    // ---- h0 = 0 (buffer 0 only; buffer 1 fully written each odd step) ----
    for (int i = tid; i < BN * HID / 2; i += NT) ((float*)hT[0])[i] = 0.0f;
    __syncthreads();

#define RNN_STEP(T, RD, WR)                                                   \
    {                                                                         \
        const char* hb = (const char*)hT[RD];                                 \
        f16x8 bfr[8];                                                         \
        _Pragma("unroll")                                                     \
        for (int ks = 0; ks < 8; ++ks)                                        \
            bfr[ks] = *(const f16x8*)(hb + roff[ks]);                         \
        const float xv = xs[T][n16];                                          \
        f32x4 acc[4];                                                         \
        _Pragma("unroll")                                                     \
        for (int mt = 0; mt < 4; ++mt)                                        \
            acc[mt] = __builtin_amdgcn_mfma_f32_16x16x32_f16(                 \
                afrag[mt][0], bfr[0], bias[mt], 0, 0, 0);                     \
        _Pragma("unroll")                                                     \
        for (int ks = 1; ks < 8; ++ks)                                        \
            _Pragma("unroll")                                                 \
            for (int mt = 0; mt < 4; ++mt)                                    \
                acc[mt] = __builtin_amdgcn_mfma_f32_16x16x32_f16(             \
                    afrag[mt][ks], bfr[ks], acc[mt], 0, 0, 0);                \
        char* wb = (char*)hT[WR];                                             \
        _Pragma("unroll")                                                     \
        for (int mt = 0; mt < 4; ++mt) {                                      \
            f16x4 h4;                                                         \
            _Pragma("unroll")                                                 \
            for (int r = 0; r < 4; ++r) {                                     \
                float s  = fmaf(wxv[mt][r], xv, acc[mt][r]);                  \
                float ex = __builtin_amdgcn_exp2f(s);                         \
                float rc = __builtin_amdgcn_rcpf(ex + 1.0f);                  \
                h4[r] = (_Float16)(1.0f - 2.0f * rc);                         \
            }                                                                 \
            *(f16x4*)(wb + woff[mt]) = h4;                                    \
        }                                                                     \
        __syncthreads();                                                      \
    }

    for (int t = 0; t < SEQ; t += 2) {
        RNN_STEP(t, 0, 1);
        RNN_STEP(t + 1, 1, 0);
    }
#undef RNN_STEP

    // ---- output: out[b][c] = b_p[c] + sum_j W_ph[c][j] * h_final[j][b] ----
    // final h in hT[0]; element (n=b, k=j) at chunk (j>>3)^(b&7)
    if (tid < BN * NCLS) {
        const int b = tid / NCLS, c = tid % NCLS;
        float sum = b_p[c];
        const _Float16* hp = hT[0][b];
        for (int j = 0; j < HID; ++j) {
            const int ph = ((((j >> 3) ^ (b & 7)) << 3) | (j & 7));
            sum += W_ph[c * HID + j] * (float)hp[ph];
        }
        out[(b0 + b) * NCLS + c] = sum;
    }
}

extern "C" void kernel_launch(void* const* d_in, const int* in_sizes, int n_in,
                              void* d_out, int out_size, void* d_ws, size_t ws_size,
                              hipStream_t stream) {
    const float* x    = (const float*)d_in[0];
    const float* W_hx = (const float*)d_in[1];
    const float* W_hh = (const float*)d_in[2];
    const float* W_ph = (const float*)d_in[3];
    const float* b_h  = (const float*)d_in[4];
    const float* b_p  = (const float*)d_in[5];
    float* out = (float*)d_out;

    rnn_mfma<<<dim3(2048 / BN), dim3(NT), 0, stream>>>(
        x, W_hx, W_hh, W_ph, b_h, b_p, out);
}

// Round 6
// 329.520 us; speedup vs baseline: 95.4189x; 1.2046x over previous
//
#include <hip/hip_runtime.h>

// VanillaRNN: S=512, I=1, H=256, C=10, B=2048, fp32 in/out.
// R6: 128 blocks x 8 waves (NT=512, 2 waves/SIMD -> TLP hides latency and
// epilogue under the LDS pipe; R5's 1 wave/SIMD fully serialized phases:
// 1712 cyc/step vs ~900 pipe-sum). Wave owns 32 rows = 2 m-tiles.
// x-term folded into MFMA C-operand (C = b_h + W_hx*x_t), x prefetched 1
// step ahead. hT XOR-swizzled (chunk c of row n at c^(n&7)), pitch 256.
// Weights pre-scaled by 2*log2e: tanh = 1 - 2*rcp(exp2(s)+1).
// waves_per_eu(2,2): 256-VGPR budget, demand ~170 -> no spill (R1/R2 lesson).

#define SEQ   512
#define HID   256
#define NCLS  10
#define BN    16      // batch per block
#define NT    512     // 8 waves

typedef _Float16 f16x8 __attribute__((ext_vector_type(8)));
typedef _Float16 f16x4 __attribute__((ext_vector_type(4)));
typedef float    f32x4 __attribute__((ext_vector_type(4)));

__global__ __launch_bounds__(NT)
__attribute__((amdgpu_waves_per_eu(2, 2)))
void rnn_mfma(
    const float* __restrict__ x,     // [B, S]
    const float* __restrict__ W_hx,  // [H]
    const float* __restrict__ W_hh,  // [H, H]
    const float* __restrict__ W_ph,  // [C, H]
    const float* __restrict__ b_h,   // [H]
    const float* __restrict__ b_p,   // [C]
    float* __restrict__ out)         // [B, C]
{
    // hT[buf][n][k]: k-chunk c (8 f16) stored at physical chunk c ^ (n&7)
    __shared__ __align__(16) _Float16 hT[2][BN][HID];    // 16 KB
    __shared__ __align__(16) float xs[SEQ + 2][BN];      // 32.9 KB

    const int tid  = threadIdx.x;
    const int lane = tid & 63;
    const int wave = tid >> 6;       // 0..7
    const int n16  = lane & 15;
    const int quad = lane >> 4;      // 0..3
    const int e    = n16 & 7;
    const int b0   = blockIdx.x * BN;

    const float SC = 2.885390081777926814f;   // 2*log2(e)

    // ---- A-frags: rows [wave*32, wave*32+32), pre-scaled by SC, f16 ----
    // A[m = n16][k = quad*8 + j]
    f16x8 afrag[2][8];
#pragma unroll
    for (int mt = 0; mt < 2; ++mt) {
        const int row = wave * 32 + mt * 16 + n16;
#pragma unroll
        for (int ks = 0; ks < 8; ++ks) {
            const float4* p = (const float4*)&W_hh[row * HID + ks * 32 + quad * 8];
            float4 u = p[0], v = p[1];
            f16x8 a;
            a[0] = (_Float16)(SC * u.x); a[1] = (_Float16)(SC * u.y);
            a[2] = (_Float16)(SC * u.z); a[3] = (_Float16)(SC * u.w);
            a[4] = (_Float16)(SC * v.x); a[5] = (_Float16)(SC * v.y);
            a[6] = (_Float16)(SC * v.z); a[7] = (_Float16)(SC * v.w);
            afrag[mt][ks] = a;
        }
    }
    // D rows for this lane: row = wave*32 + mt*16 + quad*4 + r
    f32x4 bias[2], wxv[2];
#pragma unroll
    for (int mt = 0; mt < 2; ++mt)
#pragma unroll
        for (int r = 0; r < 4; ++r) {
            const int row = wave * 32 + mt * 16 + quad * 4 + r;
            bias[mt][r] = SC * b_h[row];
            wxv[mt][r]  = SC * W_hx[row];
        }

    // ---- precomputed swizzled byte offsets (within one buffer) ----
    int roff[8], woff[2];
#pragma unroll
    for (int ks = 0; ks < 8; ++ks)
        roff[ks] = (n16 * HID + (((4 * ks + quad) ^ e) << 3)) * 2;
#pragma unroll
    for (int mt = 0; mt < 2; ++mt)
        woff[mt] = (n16 * HID +
                    (((4 * wave + 2 * mt + (quad >> 1)) ^ e) << 3) +
                    (quad & 1) * 4) * 2;

    // ---- stage xs[t][n] = x[b0+n][t] ----
    for (int i = tid; i < BN * SEQ / 4; i += NT) {
        const int n = i >> 7, t4 = (i & 127) * 4;
        float4 v = *(const float4*)&x[(b0 + n) * SEQ + t4];
        xs[t4 + 0][n] = v.x; xs[t4 + 1][n] = v.y;
        xs[t4 + 2][n] = v.z; xs[t4 + 3][n] = v.w;
    }
    // ---- h0 = 0 (buffer 0 only; buffer 1 fully written each odd step) ----
    for (int i = tid; i < BN * HID / 2; i += NT) ((float*)hT[0])[i] = 0.0f;
    __syncthreads();

    float xv = xs[0][n16];   // prefetched x_t for step 0

#define RNN_STEP(T, RD, WR)                                                   \
    {                                                                         \
        const float xnxt = xs[(T) + 1][n16];  /* prefetch next step's x */    \
        const char* hb = (const char*)hT[RD];                                 \
        f16x8 bfr[8];                                                         \
        _Pragma("unroll")                                                     \
        for (int ks = 0; ks < 8; ++ks)                                        \
            bfr[ks] = *(const f16x8*)(hb + roff[ks]);                         \
        f32x4 acc[2];                                                         \
        _Pragma("unroll")                                                     \
        for (int mt = 0; mt < 2; ++mt) {                                      \
            f32x4 c0;                                                         \
            _Pragma("unroll")                                                 \
            for (int r = 0; r < 4; ++r)                                       \
                c0[r] = fmaf(wxv[mt][r], xv, bias[mt][r]);                    \
            acc[mt] = __builtin_amdgcn_mfma_f32_16x16x32_f16(                 \
                afrag[mt][0], bfr[0], c0, 0, 0, 0);                           \
        }                                                                     \
        _Pragma("unroll")                                                     \
        for (int ks = 1; ks < 8; ++ks)                                        \
            _Pragma("unroll")                                                 \
            for (int mt = 0; mt < 2; ++mt)                                    \
                acc[mt] = __builtin_amdgcn_mfma_f32_16x16x32_f16(             \
                    afrag[mt][ks], bfr[ks], acc[mt], 0, 0, 0);                \
        char* wb = (char*)hT[WR];                                             \
        _Pragma("unroll")                                                     \
        for (int mt = 0; mt < 2; ++mt) {                                      \
            f16x4 h4;                                                         \
            _Pragma("unroll")                                                 \
            for (int r = 0; r < 4; ++r) {                                     \
                float ex = __builtin_amdgcn_exp2f(acc[mt][r]);                \
                float rc = __builtin_amdgcn_rcpf(ex + 1.0f);                  \
                h4[r] = (_Float16)(1.0f - 2.0f * rc);                         \
            }                                                                 \
            *(f16x4*)(wb + woff[mt]) = h4;                                    \
        }                                                                     \
        xv = xnxt;                                                            \
        __syncthreads();                                                      \
    }

    for (int t = 0; t < SEQ; t += 2) {
        RNN_STEP(t, 0, 1);
        RNN_STEP(t + 1, 1, 0);
    }
#undef RNN_STEP

    // ---- output: out[b][c] = b_p[c] + sum_j W_ph[c][j] * h_final[j][b] ----
    // final h in hT[0]; element (n=b, k=j) at chunk (j>>3)^(b&7)
    if (tid < BN * NCLS) {
        const int b = tid / NCLS, c = tid % NCLS;
        float sum = b_p[c];
        const _Float16* hp = hT[0][b];
        for (int j = 0; j < HID; ++j) {
            const int ph = ((((j >> 3) ^ (b & 7)) << 3) | (j & 7));
            sum += W_ph[c * HID + j] * (float)hp[ph];
        }
        out[(b0 + b) * NCLS + c] = sum;
    }
}

extern "C" void kernel_launch(void* const* d_in, const int* in_sizes, int n_in,
                              void* d_out, int out_size, void* d_ws, size_t ws_size,
                              hipStream_t stream) {
    const float* x    = (const float*)d_in[0];
    const float* W_hx = (const float*)d_in[1];
    const float* W_hh = (const float*)d_in[2];
    const float* W_ph = (const float*)d_in[3];
    const float* b_h  = (const float*)d_in[4];
    const float* b_p  = (const float*)d_in[5];
    float* out = (float*)d_out;

    rnn_mfma<<<dim3(2048 / BN), dim3(NT), 0, stream>>>(
        x, W_hx, W_hh, W_ph, b_h, b_p, out);
}